// Round 6
// baseline (175.385 us; speedup 1.0000x reference)
//
#include <hip/hip_runtime.h>
#include <hip/hip_bf16.h>
#include <math.h>

#define ENC2 1024
#define DECD 1024
#define ATT 512
#define NBATCH 32
#define SEQ 2048
#define MTOT (NBATCH*SEQ)

#define BM 128
#define BN2 256
#define BK 32

typedef __attribute__((ext_vector_type(8))) short short8;
typedef __attribute__((ext_vector_type(4))) short short4v;
typedef __attribute__((ext_vector_type(4))) float f32x4;

static __device__ __forceinline__ unsigned pk2(float a, float b) {
  __hip_bfloat162 h = __float22bfloat162_rn(float2{a, b});  // v_cvt_pk_bf16_f32
  union { __hip_bfloat162 h; unsigned u; } c; c.h = h;
  return c.u;
}

static __device__ __forceinline__ float fast_tanh(float x) {
  float ax = fabsf(x);
  float e = __expf(2.f * ax);
  float t = 1.f - 2.f / (e + 1.f);
  return copysignf(t, x);
}

static __device__ __forceinline__ void gload_lds16(const void* g, void* l) {
  __builtin_amdgcn_global_load_lds(
      (const __attribute__((address_space(1))) void*)g,
      (__attribute__((address_space(3))) void*)l, 16, 0, 0);
}

// ---- U_w [ENC2][ATT] f32  ->  U_wT [ATT][ENC2] bf16 ----
__global__ __launch_bounds__(256) void uwT_kernel(const float* __restrict__ U_w,
                                                  short* __restrict__ U_wT) {
  __shared__ float tile[64][65];
  const int kt = blockIdx.x >> 3;
  const int ct = blockIdx.x & 7;
  const int k0 = kt * 64, c0 = ct * 64;
  const int t = threadIdx.x;
  const int r = t >> 4, cc = (t & 15) * 4;
  #pragma unroll
  for (int p = 0; p < 4; p++) {
    float4 v = *(const float4*)(U_w + (size_t)(k0 + r + p*16) * ATT + c0 + cc);
    tile[r + p*16][cc+0] = v.x; tile[r + p*16][cc+1] = v.y;
    tile[r + p*16][cc+2] = v.z; tile[r + p*16][cc+3] = v.w;
  }
  __syncthreads();
  const int cr = t >> 4, kk = (t & 15) * 4;
  #pragma unroll
  for (int p = 0; p < 4; p++) {
    int c = cr + p*16;
    unsigned u0 = pk2(tile[kk + 0][c], tile[kk + 1][c]);
    unsigned u1 = pk2(tile[kk + 2][c], tile[kk + 3][c]);
    union { short4v s; unsigned u[2]; } o; o.u[0] = u0; o.u[1] = u1;
    *(short4v*)(U_wT + (size_t)(c0 + c) * ENC2 + k0 + kk) = o.s;
  }
}

// ---- Wsb[b][a] = dh[b]·W_w[:,a] + W_b[a] + U_b[a] ----
__global__ __launch_bounds__(512) void ws_kernel(const float* __restrict__ dh,
                                                 const float* __restrict__ W_w,
                                                 const float* __restrict__ W_b,
                                                 const float* __restrict__ U_b,
                                                 float* __restrict__ Wsb) {
  __shared__ float dsh[DECD];
  __shared__ float part[4][128];
  const int b  = blockIdx.x >> 2;
  const int a0 = (blockIdx.x & 3) * 128;
  const int t = threadIdx.x;
  for (int i = t; i < DECD; i += 512) dsh[i] = dh[(size_t)b * DECD + i];
  __syncthreads();
  const int ks = t >> 7;
  const int a  = t & 127;
  const float* wp = W_w + (size_t)(ks * 256) * ATT + a0 + a;
  float s0 = 0.f, s1 = 0.f, s2 = 0.f, s3 = 0.f;
  #pragma unroll 4
  for (int kk = 0; kk < 256; kk += 4) {
    s0 = fmaf(dsh[ks*256 + kk + 0], wp[(size_t)(kk + 0) * ATT], s0);
    s1 = fmaf(dsh[ks*256 + kk + 1], wp[(size_t)(kk + 1) * ATT], s1);
    s2 = fmaf(dsh[ks*256 + kk + 2], wp[(size_t)(kk + 2) * ATT], s2);
    s3 = fmaf(dsh[ks*256 + kk + 3], wp[(size_t)(kk + 3) * ATT], s3);
  }
  part[ks][a] = (s0 + s1) + (s2 + s3);
  __syncthreads();
  if (t < 128) {
    float v = part[0][t] + part[1][t] + part[2][t] + part[3][t];
    Wsb[(size_t)b * ATT + a0 + t] = v + W_b[a0 + t] + U_b[a0 + t];
  }
}

// LDS layouts (dense-linear wave64 b128 reads):
//   A f32 : [m_sub(8)][half(2)][kh(4)][fr(16)][4 f32]  = 16 KB/buf, 3 bufs
//   B bf16: [n_sub(16)][kh(4)][fr(16)][8 bf16]         = 16 KB/buf, 2 bufs
#define COMPUTE(AB, BB)                                                        \
  do {                                                                         \
    short8 bf[4];                                                              \
    _Pragma("unroll")                                                          \
    for (int n = 0; n < 4; n++)                                                \
      bf[n] = *(const short8*)(&Bs[BB][bBase + n*512]);                        \
    _Pragma("unroll")                                                          \
    for (int m = 0; m < 4; m++) {                                              \
      const float* ap = &As[AB][aBase + m*512];                                \
      float4 a0 = *(const float4*)ap;                                          \
      float4 a1 = *(const float4*)(ap + 256);                                  \
      union { short8 s; unsigned u[4]; } aw;                                   \
      aw.u[0] = pk2(a0.x, a0.y); aw.u[1] = pk2(a0.z, a0.w);                    \
      aw.u[2] = pk2(a1.x, a1.y); aw.u[3] = pk2(a1.z, a1.w);                    \
      acc[m][0] = __builtin_amdgcn_mfma_f32_16x16x32_bf16(aw.s, bf[0], acc[m][0], 0, 0, 0); \
      acc[m][1] = __builtin_amdgcn_mfma_f32_16x16x32_bf16(aw.s, bf[1], acc[m][1], 0, 0, 0); \
      acc[m][2] = __builtin_amdgcn_mfma_f32_16x16x32_bf16(aw.s, bf[2], acc[m][2], 0, 0, 0); \
      acc[m][3] = __builtin_amdgcn_mfma_f32_16x16x32_bf16(aw.s, bf[3], acc[m][3], 0, 0, 0); \
    }                                                                          \
  } while (0)

// One K-step: issue B(kt+1), A(kt+2); compute kt; counted vmcnt leaves A(kt+2)
// in flight across the RAW barrier (no implicit vmcnt(0) drain).
#define STEP(ARD, AWR, BRD, BWR)                                               \
  do {                                                                         \
    gload_lds16(bNext,           &Bs[BWR][w*1024]);                            \
    gload_lds16(bNext + 16*ENC2, &Bs[BWR][w*1024 + 512]);                      \
    gload_lds16(aNext,           &As[AWR][w*512]);                             \
    gload_lds16(aNext + 4,       &As[AWR][w*512 + 256]);                       \
    bNext += BK; aNext += BK;                                                  \
    COMPUTE(ARD, BRD);                                                         \
    asm volatile("s_waitcnt vmcnt(2)" ::: "memory");                           \
    __builtin_amdgcn_s_barrier();                                              \
  } while (0)

__global__ __launch_bounds__(512, 4) void energy_kernel(
    const float* __restrict__ A,      // encoder [MTOT][ENC2] f32
    const short* __restrict__ Bt,     // U_wT [ATT][ENC2] bf16
    const float* __restrict__ Wsb,    // [NBATCH][ATT]
    const float* __restrict__ vw,     // [ATT]
    float* __restrict__ epart)        // [2][MTOT]
{
  __shared__ __align__(16) float As[3][4096];   // 48 KB
  __shared__ __align__(16) short Bs[2][8192];   // 32 KB -> 80 KB total, 2 blk/CU

  const int tid = threadIdx.x;
  const int bid = blockIdx.x;
  const int mt = (bid >> 4) * 8 + (bid & 7);   // XCD pairing: nt pair shares bid%8
  const int nt = (bid >> 3) & 1;
  const int row0 = mt * BM;
  const int col0 = nt * BN2;
  const int bidx = row0 / SEQ;

  const int lane = tid & 63;
  const int w    = tid >> 6;
  const int wm   = w >> 2;
  const int wn   = w & 3;
  const int fr   = lane & 15;
  const int kh   = lane >> 4;

  const int aBase = wm*2048 + kh*64 + fr*4;    // + m*512 (+256 for half=1)
  const int bBase = wn*2048 + kh*128 + fr*8;   // + n*512

  f32x4 acc[4][4];
  #pragma unroll
  for (int m = 0; m < 4; m++)
    #pragma unroll
    for (int n = 0; n < 4; n++) acc[m][n] = (f32x4){0.f, 0.f, 0.f, 0.f};

  // staging sources: lane l -> (fr=l&15, kh=l>>4) matching its linear LDS slot
  const float* aSrc = A + (size_t)(row0 + w*16 + (lane & 15)) * ENC2 + (lane >> 4) * 8;
  const short* bSrc = Bt + (size_t)(col0 + 2*w*16 + (lane & 15)) * ENC2
                         + ((lane >> 4) & 3) * 8;

  // prologue: A0, B0, A1 (order matters for vmcnt counting)
  gload_lds16(aSrc,            &As[0][w*512]);
  gload_lds16(aSrc + 4,        &As[0][w*512 + 256]);
  gload_lds16(bSrc,            &Bs[0][w*1024]);
  gload_lds16(bSrc + 16*ENC2,  &Bs[0][w*1024 + 512]);
  gload_lds16(aSrc + 32,       &As[1][w*512]);
  gload_lds16(aSrc + 36,       &As[1][w*512 + 256]);
  asm volatile("s_waitcnt vmcnt(2)" ::: "memory");   // A0,B0 done; A1 in flight
  __builtin_amdgcn_s_barrier();

  const float* aNext = aSrc + 64;   // tile kt=2
  const short* bNext = bSrc + 32;   // tile kt=1

  // kt = 0..29 (period-6 buffer pattern)
  for (int t6 = 0; t6 < 5; t6++) {
    STEP(0, 2, 0, 1);
    STEP(1, 0, 1, 0);
    STEP(2, 1, 0, 1);
    STEP(0, 2, 1, 0);
    STEP(1, 0, 0, 1);
    STEP(2, 1, 1, 0);
  }
  // kt = 30: stage B31 only; drain everything before the last tile
  gload_lds16(bNext,           &Bs[1][w*1024]);
  gload_lds16(bNext + 16*ENC2, &Bs[1][w*1024 + 512]);
  COMPUTE(0, 0);
  asm volatile("s_waitcnt vmcnt(0)" ::: "memory");
  __builtin_amdgcn_s_barrier();
  // kt = 31
  COMPUTE(1, 1);

  // epilogue: tanh + v-dot; lane-reduce over cols, cross-wn reduce via LDS
  float* eps = (float*)&As[0][0];   // all DMA drained; As[0] free
  float vv[4], wsb[4];
  #pragma unroll
  for (int n = 0; n < 4; n++) {
    const int gc = col0 + wn*64 + n*16 + fr;
    vv[n]  = vw[gc];
    wsb[n] = Wsb[(size_t)bidx * ATT + gc];
  }
  const int rg = lane >> 4;
  #pragma unroll
  for (int m = 0; m < 4; m++) {
    float part[4] = {0.f, 0.f, 0.f, 0.f};
    #pragma unroll
    for (int n = 0; n < 4; n++) {
      #pragma unroll
      for (int r = 0; r < 4; r++)
        part[r] += vv[n] * fast_tanh(acc[m][n][r] + wsb[n]);
    }
    #pragma unroll
    for (int r = 0; r < 4; r++) {
      float p = part[r];
      p += __shfl_xor(p, 1);
      p += __shfl_xor(p, 2);
      p += __shfl_xor(p, 4);
      p += __shfl_xor(p, 8);
      if (fr == 0) eps[wn*BM + wm*64 + m*16 + rg*4 + r] = p;
    }
  }
  __syncthreads();
  if (tid < BM) {
    float s = eps[0*BM + tid] + eps[1*BM + tid] + eps[2*BM + tid] + eps[3*BM + tid];
    epart[(size_t)nt * MTOT + row0 + tid] = s;
  }
}

// ---- softmax over S=2048 per batch row (sums the 2 partials) ----
__global__ __launch_bounds__(256) void softmax_kernel(const float* __restrict__ epart,
                                                      float* __restrict__ out) {
  __shared__ float redmax[4];
  __shared__ float redsum[4];
  const int b = blockIdx.x, t = threadIdx.x;
  const float* e0 = epart + (size_t)b * SEQ;
  const float* e1 = epart + (size_t)MTOT + (size_t)b * SEQ;
  float vals[8];
  float mx = -1e30f;
  #pragma unroll
  for (int i = 0; i < 8; i++) {
    vals[i] = e0[t + i*256] + e1[t + i*256];
    mx = fmaxf(mx, vals[i]);
  }
  #pragma unroll
  for (int off = 1; off < 64; off <<= 1) mx = fmaxf(mx, __shfl_xor(mx, off));
  if ((t & 63) == 0) redmax[t >> 6] = mx;
  __syncthreads();
  mx = fmaxf(fmaxf(redmax[0], redmax[1]), fmaxf(redmax[2], redmax[3]));
  float sum = 0.f;
  #pragma unroll
  for (int i = 0; i < 8; i++) { vals[i] = expf(vals[i] - mx); sum += vals[i]; }
  #pragma unroll
  for (int off = 1; off < 64; off <<= 1) sum += __shfl_xor(sum, off);
  if ((t & 63) == 0) redsum[t >> 6] = sum;
  __syncthreads();
  const float inv = 1.f / (redsum[0] + redsum[1] + redsum[2] + redsum[3]);
  #pragma unroll
  for (int i = 0; i < 8; i++) out[(size_t)b * SEQ + t + i*256] = vals[i] * inv;
}

extern "C" void kernel_launch(void* const* d_in, const int* in_sizes, int n_in,
                              void* d_out, int out_size, void* d_ws, size_t ws_size,
                              hipStream_t stream) {
  const float* dh  = (const float*)d_in[0];
  const float* enc = (const float*)d_in[1];
  const float* W_w = (const float*)d_in[2];
  const float* W_b = (const float*)d_in[3];
  const float* U_w = (const float*)d_in[4];
  const float* U_b = (const float*)d_in[5];
  const float* v_w = (const float*)d_in[6];
  float* out = (float*)d_out;

  char* ws = (char*)d_ws;
  float* epart = (float*)ws;                      // 512 KB
  float* Wsb   = (float*)(ws + 512 * 1024);       // 64 KB
  short* U_wT  = (short*)(ws + 576 * 1024);       // 1 MB

  uwT_kernel<<<128, 256, 0, stream>>>(U_w, U_wT);
  ws_kernel<<<128, 512, 0, stream>>>(dh, W_w, W_b, U_b, Wsb);
  energy_kernel<<<1024, 512, 0, stream>>>(enc, U_wT, Wsb, v_w, epart);
  softmax_kernel<<<NBATCH, 256, 0, stream>>>(epart, out);
}

// Round 7
// 162.400 us; speedup vs baseline: 1.0800x; 1.0800x over previous
//
#include <hip/hip_runtime.h>
#include <hip/hip_bf16.h>
#include <math.h>

#define ENC2 1024
#define DECD 1024
#define ATT 512
#define NBATCH 32
#define SEQ 2048
#define MTOT (NBATCH*SEQ)

#define BM 128
#define BN2 256
#define BK 32

typedef __attribute__((ext_vector_type(8))) short short8;
typedef __attribute__((ext_vector_type(4))) short short4v;
typedef __attribute__((ext_vector_type(4))) float f32x4;

static __device__ __forceinline__ unsigned pk2(float a, float b) {
  __hip_bfloat162 h = __float22bfloat162_rn(float2{a, b});  // v_cvt_pk_bf16_f32
  union { __hip_bfloat162 h; unsigned u; } c; c.h = h;
  return c.u;
}

static __device__ __forceinline__ float fast_tanh(float x) {
  float ax = fabsf(x);
  float e = __expf(2.f * ax);
  float t = 1.f - 2.f / (e + 1.f);
  return copysignf(t, x);
}

// ---- U_w [ENC2][ATT] f32  ->  U_wT [ATT][ENC2] bf16 ----
__global__ __launch_bounds__(256) void uwT_kernel(const float* __restrict__ U_w,
                                                  short* __restrict__ U_wT) {
  __shared__ float tile[64][65];
  const int kt = blockIdx.x >> 3;
  const int ct = blockIdx.x & 7;
  const int k0 = kt * 64, c0 = ct * 64;
  const int t = threadIdx.x;
  const int r = t >> 4, cc = (t & 15) * 4;
  #pragma unroll
  for (int p = 0; p < 4; p++) {
    float4 v = *(const float4*)(U_w + (size_t)(k0 + r + p*16) * ATT + c0 + cc);
    tile[r + p*16][cc+0] = v.x; tile[r + p*16][cc+1] = v.y;
    tile[r + p*16][cc+2] = v.z; tile[r + p*16][cc+3] = v.w;
  }
  __syncthreads();
  const int cr = t >> 4, kk = (t & 15) * 4;
  #pragma unroll
  for (int p = 0; p < 4; p++) {
    int c = cr + p*16;
    unsigned u0 = pk2(tile[kk + 0][c], tile[kk + 1][c]);
    unsigned u1 = pk2(tile[kk + 2][c], tile[kk + 3][c]);
    union { short4v s; unsigned u[2]; } o; o.u[0] = u0; o.u[1] = u1;
    *(short4v*)(U_wT + (size_t)(c0 + c) * ENC2 + k0 + kk) = o.s;
  }
}

// ---- Wsb[b][a] = dh[b]·W_w[:,a] + W_b[a] + U_b[a] ----
__global__ __launch_bounds__(512) void ws_kernel(const float* __restrict__ dh,
                                                 const float* __restrict__ W_w,
                                                 const float* __restrict__ W_b,
                                                 const float* __restrict__ U_b,
                                                 float* __restrict__ Wsb) {
  __shared__ float dsh[DECD];
  __shared__ float part[4][128];
  const int b  = blockIdx.x >> 2;
  const int a0 = (blockIdx.x & 3) * 128;
  const int t = threadIdx.x;
  for (int i = t; i < DECD; i += 512) dsh[i] = dh[(size_t)b * DECD + i];
  __syncthreads();
  const int ks = t >> 7;
  const int a  = t & 127;
  const float* wp = W_w + (size_t)(ks * 256) * ATT + a0 + a;
  float s0 = 0.f, s1 = 0.f, s2 = 0.f, s3 = 0.f;
  #pragma unroll 4
  for (int kk = 0; kk < 256; kk += 4) {
    s0 = fmaf(dsh[ks*256 + kk + 0], wp[(size_t)(kk + 0) * ATT], s0);
    s1 = fmaf(dsh[ks*256 + kk + 1], wp[(size_t)(kk + 1) * ATT], s1);
    s2 = fmaf(dsh[ks*256 + kk + 2], wp[(size_t)(kk + 2) * ATT], s2);
    s3 = fmaf(dsh[ks*256 + kk + 3], wp[(size_t)(kk + 3) * ATT], s3);
  }
  part[ks][a] = (s0 + s1) + (s2 + s3);
  __syncthreads();
  if (t < 128) {
    float v = part[0][t] + part[1][t] + part[2][t] + part[3][t];
    Wsb[(size_t)b * ATT + a0 + t] = v + W_b[a0 + t] + U_b[a0 + t];
  }
}

// ---- main GEMM+tanh+vdot ----
// Dense fragment-native LDS (all bf16), 50 KB total -> 3 blocks/CU:
//   A: [m_sub(8)][kh(4)][fr(16)][8]  = 8 KB/buf  x2
//   B: [n_sub(16)][kh(4)][fr(16)][8] = 16 KB/buf x2
// Staging (reg-pack): thread t = w*64 + kh*16 + fr handles subtile slot t*8.
__global__ __launch_bounds__(512, 4) void energy_kernel(
    const float* __restrict__ A,      // encoder [MTOT][ENC2] f32
    const short* __restrict__ Bt,     // U_wT [ATT][ENC2] bf16
    const float* __restrict__ Wsb,    // [NBATCH][ATT]
    const float* __restrict__ vw,     // [ATT]
    float* __restrict__ epart)        // [2][MTOT]
{
  __shared__ __align__(16) short As[2][4096];   // 16 KB
  __shared__ __align__(16) short Bs[2][8192];   // 32 KB
  __shared__ float eps[4][BM];                  // 2 KB  -> 50 KB total

  const int tid = threadIdx.x;
  const int bid = blockIdx.x;
  const int mt = (bid >> 4) * 8 + (bid & 7);   // XCD pairing: nt pair shares bid%8
  const int nt = (bid >> 3) & 1;
  const int row0 = mt * BM;
  const int col0 = nt * BN2;
  const int bidx = row0 / SEQ;

  const int lane = tid & 63;
  const int w    = tid >> 6;
  const int wm   = w >> 2;
  const int wn   = w & 3;
  const int fr   = lane & 15;
  const int kh   = lane >> 4;

  // staging identity: thread t covers (sub = w, kh_s, fr_s), LDS slot t*8
  const int fr_s = tid & 15;
  const int kh_s = (tid >> 4) & 3;
  const int sidx = tid * 8;

  const float* aSrc = A  + (size_t)(row0 + w*16 + fr_s) * ENC2 + kh_s * 8;
  const short* bSrc0 = Bt + (size_t)(col0 +       w*16 + fr_s) * ENC2 + kh_s * 8;
  const short* bSrc1 = Bt + (size_t)(col0 + 128 + w*16 + fr_s) * ENC2 + kh_s * 8;

  // fragment read bases (shorts)
  const int afBase = wm*2048 + kh*128 + fr*8;   // + m*512
  const int bfBase = wn*2048 + kh*128 + fr*8;   // + n*512

  f32x4 acc[4][4];
  #pragma unroll
  for (int m = 0; m < 4; m++)
    #pragma unroll
    for (int n = 0; n < 4; n++) acc[m][n] = (f32x4){0.f, 0.f, 0.f, 0.f};

  // prologue: stage kt=0 into buffer 0
  {
    float4 a0 = *(const float4*)(aSrc);
    float4 a1 = *(const float4*)(aSrc + 4);
    short8 b0 = *(const short8*)(bSrc0);
    short8 b1 = *(const short8*)(bSrc1);
    union { short8 s; unsigned u[4]; } aw;
    aw.u[0] = pk2(a0.x, a0.y); aw.u[1] = pk2(a0.z, a0.w);
    aw.u[2] = pk2(a1.x, a1.y); aw.u[3] = pk2(a1.z, a1.w);
    *(short8*)(&As[0][sidx]) = aw.s;
    *(short8*)(&Bs[0][sidx]) = b0;
    *(short8*)(&Bs[0][sidx + 4096]) = b1;
  }
  __syncthreads();

  for (int kt = 0; kt < 32; kt++) {
    const int cur = kt & 1;
    float4 a0, a1; short8 b0, b1;
    const bool more = (kt < 31);
    if (more) {   // prefetch kt+1 into regs; latency hides under frag reads+MFMA
      const int off = (kt + 1) * BK;
      a0 = *(const float4*)(aSrc + off);
      a1 = *(const float4*)(aSrc + off + 4);
      b0 = *(const short8*)(bSrc0 + off);
      b1 = *(const short8*)(bSrc1 + off);
    }
    short8 bf[4];
    #pragma unroll
    for (int n = 0; n < 4; n++)
      bf[n] = *(const short8*)(&Bs[cur][bfBase + n*512]);
    #pragma unroll
    for (int m = 0; m < 4; m++) {
      short8 af = *(const short8*)(&As[cur][afBase + m*512]);
      acc[m][0] = __builtin_amdgcn_mfma_f32_16x16x32_bf16(af, bf[0], acc[m][0], 0, 0, 0);
      acc[m][1] = __builtin_amdgcn_mfma_f32_16x16x32_bf16(af, bf[1], acc[m][1], 0, 0, 0);
      acc[m][2] = __builtin_amdgcn_mfma_f32_16x16x32_bf16(af, bf[2], acc[m][2], 0, 0, 0);
      acc[m][3] = __builtin_amdgcn_mfma_f32_16x16x32_bf16(af, bf[3], acc[m][3], 0, 0, 0);
    }
    if (more) {
      union { short8 s; unsigned u[4]; } aw;
      aw.u[0] = pk2(a0.x, a0.y); aw.u[1] = pk2(a0.z, a0.w);
      aw.u[2] = pk2(a1.x, a1.y); aw.u[3] = pk2(a1.z, a1.w);
      *(short8*)(&As[cur ^ 1][sidx]) = aw.s;
      *(short8*)(&Bs[cur ^ 1][sidx]) = b0;
      *(short8*)(&Bs[cur ^ 1][sidx + 4096]) = b1;
    }
    __syncthreads();
  }

  // epilogue: tanh + v-dot; lane-reduce over cols, cross-wn reduce via LDS
  float vv[4], wsb[4];
  #pragma unroll
  for (int n = 0; n < 4; n++) {
    const int gc = col0 + wn*64 + n*16 + fr;
    vv[n]  = vw[gc];
    wsb[n] = Wsb[(size_t)bidx * ATT + gc];
  }
  const int rg = lane >> 4;
  #pragma unroll
  for (int m = 0; m < 4; m++) {
    float part[4] = {0.f, 0.f, 0.f, 0.f};
    #pragma unroll
    for (int n = 0; n < 4; n++) {
      #pragma unroll
      for (int r = 0; r < 4; r++)
        part[r] += vv[n] * fast_tanh(acc[m][n][r] + wsb[n]);
    }
    #pragma unroll
    for (int r = 0; r < 4; r++) {
      float p = part[r];
      p += __shfl_xor(p, 1);
      p += __shfl_xor(p, 2);
      p += __shfl_xor(p, 4);
      p += __shfl_xor(p, 8);
      if (fr == 0) eps[wn][wm*64 + m*16 + rg*4 + r] = p;
    }
  }
  __syncthreads();
  if (tid < BM) {
    float s = eps[0][tid] + eps[1][tid] + eps[2][tid] + eps[3][tid];
    epart[(size_t)nt * MTOT + row0 + tid] = s;
  }
}

// ---- softmax over S=2048 per batch row (sums the 2 partials) ----
__global__ __launch_bounds__(256) void softmax_kernel(const float* __restrict__ epart,
                                                      float* __restrict__ out) {
  __shared__ float redmax[4];
  __shared__ float redsum[4];
  const int b = blockIdx.x, t = threadIdx.x;
  const float* e0 = epart + (size_t)b * SEQ;
  const float* e1 = epart + (size_t)MTOT + (size_t)b * SEQ;
  float vals[8];
  float mx = -1e30f;
  #pragma unroll
  for (int i = 0; i < 8; i++) {
    vals[i] = e0[t + i*256] + e1[t + i*256];
    mx = fmaxf(mx, vals[i]);
  }
  #pragma unroll
  for (int off = 1; off < 64; off <<= 1) mx = fmaxf(mx, __shfl_xor(mx, off));
  if ((t & 63) == 0) redmax[t >> 6] = mx;
  __syncthreads();
  mx = fmaxf(fmaxf(redmax[0], redmax[1]), fmaxf(redmax[2], redmax[3]));
  float sum = 0.f;
  #pragma unroll
  for (int i = 0; i < 8; i++) { vals[i] = expf(vals[i] - mx); sum += vals[i]; }
  #pragma unroll
  for (int off = 1; off < 64; off <<= 1) sum += __shfl_xor(sum, off);
  if ((t & 63) == 0) redsum[t >> 6] = sum;
  __syncthreads();
  const float inv = 1.f / (redsum[0] + redsum[1] + redsum[2] + redsum[3]);
  #pragma unroll
  for (int i = 0; i < 8; i++) out[(size_t)b * SEQ + t + i*256] = vals[i] * inv;
}

extern "C" void kernel_launch(void* const* d_in, const int* in_sizes, int n_in,
                              void* d_out, int out_size, void* d_ws, size_t ws_size,
                              hipStream_t stream) {
  const float* dh  = (const float*)d_in[0];
  const float* enc = (const float*)d_in[1];
  const float* W_w = (const float*)d_in[2];
  const float* W_b = (const float*)d_in[3];
  const float* U_w = (const float*)d_in[4];
  const float* U_b = (const float*)d_in[5];
  const float* v_w = (const float*)d_in[6];
  float* out = (float*)d_out;

  char* ws = (char*)d_ws;
  float* epart = (float*)ws;                      // 512 KB
  float* Wsb   = (float*)(ws + 512 * 1024);       // 64 KB
  short* U_wT  = (short*)(ws + 576 * 1024);       // 1 MB

  uwT_kernel<<<128, 256, 0, stream>>>(U_w, U_wT);
  ws_kernel<<<128, 512, 0, stream>>>(dh, W_w, W_b, U_b, Wsb);
  energy_kernel<<<1024, 512, 0, stream>>>(enc, U_wT, Wsb, v_w, epart);
  softmax_kernel<<<NBATCH, 256, 0, stream>>>(epart, out);
}

// Round 8
// 134.414 us; speedup vs baseline: 1.3048x; 1.2082x over previous
//
#include <hip/hip_runtime.h>
#include <hip/hip_bf16.h>
#include <math.h>

#define ENC2 1024
#define DECD 1024
#define ATT 512
#define NBATCH 32
#define SEQ 2048
#define MTOT (NBATCH*SEQ)

#define BM 128
#define BN2 256
#define BK 32
#define LDK 40   // padded LDS row stride (80 B -> only 2-way bank alias, free per m136)

typedef __attribute__((ext_vector_type(8))) short short8;
typedef __attribute__((ext_vector_type(4))) short short4v;
typedef __attribute__((ext_vector_type(4))) float f32x4;

static __device__ __forceinline__ unsigned pk2(float a, float b) {
  __hip_bfloat162 h = __float22bfloat162_rn(float2{a, b});  // v_cvt_pk_bf16_f32 (RNE)
  union { __hip_bfloat162 h; unsigned u; } c; c.h = h;
  return c.u;
}

static __device__ __forceinline__ float fast_tanh(float x) {
  float ax = fabsf(x);
  float e = __expf(2.f * ax);          // overflow -> inf -> t -> 1 (correct)
  float t = 1.f - 2.f / (e + 1.f);
  return copysignf(t, x);
}

// ---- fused prep: blocks 0..127 transpose U_w -> U_wT bf16; blocks 128..255
//      compute Wsb[b][a] = dh[b]·W_w[:,a] + W_b[a] + U_b[a] ----
__global__ __launch_bounds__(512) void prep_kernel(
    const float* __restrict__ U_w, short* __restrict__ U_wT,
    const float* __restrict__ dh, const float* __restrict__ W_w,
    const float* __restrict__ W_b, const float* __restrict__ U_b,
    float* __restrict__ Wsb) {
  __shared__ float tile[64][65];      // uwT path (16.6 KB)
  __shared__ float dsh[DECD];         // ws path (4 KB)
  __shared__ float part[4][128];      // ws path (2 KB)
  const int t = threadIdx.x;

  if (blockIdx.x < 128) {
    // ---- U_w [ENC2][ATT] f32 -> U_wT [ATT][ENC2] bf16, 64x64 tiles ----
    const int kt = blockIdx.x >> 3;      // 16 k-tiles
    const int ct = blockIdx.x & 7;       // 8 c-tiles
    const int k0 = kt * 64, c0 = ct * 64;
    const int r = t >> 3, cc = (t & 7) * 8;
    float4 v0 = *(const float4*)(U_w + (size_t)(k0 + r) * ATT + c0 + cc);
    float4 v1 = *(const float4*)(U_w + (size_t)(k0 + r) * ATT + c0 + cc + 4);
    tile[r][cc+0] = v0.x; tile[r][cc+1] = v0.y; tile[r][cc+2] = v0.z; tile[r][cc+3] = v0.w;
    tile[r][cc+4] = v1.x; tile[r][cc+5] = v1.y; tile[r][cc+6] = v1.z; tile[r][cc+7] = v1.w;
    __syncthreads();
    const int c = t >> 3, kk = (t & 7) * 8;
    union { short8 s; unsigned u[4]; } o;
    o.u[0] = pk2(tile[kk+0][c], tile[kk+1][c]);
    o.u[1] = pk2(tile[kk+2][c], tile[kk+3][c]);
    o.u[2] = pk2(tile[kk+4][c], tile[kk+5][c]);
    o.u[3] = pk2(tile[kk+6][c], tile[kk+7][c]);
    *(short8*)(U_wT + (size_t)(c0 + c) * ENC2 + k0 + kk) = o.s;
  } else {
    // ---- Wsb, K-split x4, 128-col slices ----
    const int bid = blockIdx.x - 128;
    const int b  = bid >> 2;
    const int a0 = (bid & 3) * 128;
    for (int i = t; i < DECD; i += 512) dsh[i] = dh[(size_t)b * DECD + i];
    __syncthreads();
    const int ks = t >> 7;
    const int a  = t & 127;
    const float* wp = W_w + (size_t)(ks * 256) * ATT + a0 + a;
    float s0 = 0.f, s1 = 0.f, s2 = 0.f, s3 = 0.f;
    #pragma unroll 4
    for (int kk = 0; kk < 256; kk += 4) {
      s0 = fmaf(dsh[ks*256 + kk + 0], wp[(size_t)(kk + 0) * ATT], s0);
      s1 = fmaf(dsh[ks*256 + kk + 1], wp[(size_t)(kk + 1) * ATT], s1);
      s2 = fmaf(dsh[ks*256 + kk + 2], wp[(size_t)(kk + 2) * ATT], s2);
      s3 = fmaf(dsh[ks*256 + kk + 3], wp[(size_t)(kk + 3) * ATT], s3);
    }
    part[ks][a] = (s0 + s1) + (s2 + s3);
    __syncthreads();
    if (t < 128) {
      float v = part[0][t] + part[1][t] + part[2][t] + part[3][t];
      Wsb[(size_t)b * ATT + a0 + t] = v + W_b[a0 + t] + U_b[a0 + t];
    }
  }
}

// ---- main: epart[nt][row] = sum_{a in nt-half} v[a]*tanh(enc[row]·U[:,a] + Wsb[b][a])
//      (R2 structure verbatim: best measured variant, 154 us bench) ----
__global__ __launch_bounds__(512) void energy_kernel(
    const float* __restrict__ A,      // encoder [MTOT][ENC2] f32
    const short* __restrict__ Bt,     // U_wT [ATT][ENC2] bf16
    const float* __restrict__ Wsb,    // [NBATCH][ATT]
    const float* __restrict__ vw,     // [ATT]
    float* __restrict__ epart)        // [2][MTOT]
{
  __shared__ __align__(16) short As[2][BM * LDK];
  __shared__ __align__(16) short Bs[2][BN2 * LDK];
  __shared__ float eps[4][BM];        // per-wn-wave partial energies

  const int tid = threadIdx.x;
  const int bid = blockIdx.x;
  // XCD-pairing swizzle: bids 16g+j and 16g+j+8 share mt (same A rows) and
  // have equal bid%8 -> same XCD -> A fetched once per pair from HBM.
  const int mt = (bid >> 4) * 8 + (bid & 7);   // 0..511
  const int nt = (bid >> 3) & 1;               // pair member
  const int row0 = mt * BM;
  const int col0 = nt * BN2;
  const int bidx = row0 / SEQ;

  const int lane = tid & 63;
  const int wid  = tid >> 6;
  const int wm   = wid >> 2;    // 0..1
  const int wn   = wid & 3;     // 0..3

  const int ar = tid >> 2, ak = (tid & 3) * 8;   // A staging: 128 rows, 4 thr/row, 8 f32 each
  const int bc = tid >> 1, bk = (tid & 1) * 16;  // B staging: 256 cols, 2 thr/col, 16 bf16 each

  const int fr = lane & 15;
  const int k0 = (lane >> 4) * 8;

  f32x4 acc[4][4];
  #pragma unroll
  for (int m = 0; m < 4; m++)
    #pragma unroll
    for (int n = 0; n < 4; n++) acc[m][n] = (f32x4){0.f, 0.f, 0.f, 0.f};

  const float* Abase = A + (size_t)row0 * ENC2;
  const short* Bbase = Bt + (size_t)col0 * ENC2;

  float4 aR0, aR1;
  short8 bR0, bR1;

  // prologue: stage kt=0
  aR0 = *(const float4*)(Abase + (size_t)ar * ENC2 + ak);
  aR1 = *(const float4*)(Abase + (size_t)ar * ENC2 + ak + 4);
  bR0 = *(const short8*)(Bbase + (size_t)bc * ENC2 + bk);
  bR1 = *(const short8*)(Bbase + (size_t)bc * ENC2 + bk + 8);
  {
    union { short8 s; unsigned u[4]; } w;
    w.u[0] = pk2(aR0.x, aR0.y); w.u[1] = pk2(aR0.z, aR0.w);
    w.u[2] = pk2(aR1.x, aR1.y); w.u[3] = pk2(aR1.z, aR1.w);
    *(short8*)(&As[0][ar * LDK + ak]) = w.s;
    *(short8*)(&Bs[0][bc * LDK + bk]) = bR0;
    *(short8*)(&Bs[0][bc * LDK + bk + 8]) = bR1;
  }
  __syncthreads();

  const int NT = ENC2 / BK;  // 32
  for (int kt = 0; kt < NT; kt++) {
    const int cur = kt & 1;
    const bool more = (kt + 1 < NT);
    if (more) {  // issue next-tile global loads; latency hides under ds_read+MFMA
      const float* Ab = Abase + (kt + 1) * BK;
      aR0 = *(const float4*)(Ab + (size_t)ar * ENC2 + ak);
      aR1 = *(const float4*)(Ab + (size_t)ar * ENC2 + ak + 4);
      const short* Bb = Bbase + (kt + 1) * BK;
      bR0 = *(const short8*)(Bb + (size_t)bc * ENC2 + bk);
      bR1 = *(const short8*)(Bb + (size_t)bc * ENC2 + bk + 8);
    }
    short8 af[4], bfr[4];
    #pragma unroll
    for (int m = 0; m < 4; m++)
      af[m] = *(const short8*)(&As[cur][(wm*64 + m*16 + fr) * LDK + k0]);
    #pragma unroll
    for (int n = 0; n < 4; n++)
      bfr[n] = *(const short8*)(&Bs[cur][(wn*64 + n*16 + fr) * LDK + k0]);
    #pragma unroll
    for (int m = 0; m < 4; m++)
      #pragma unroll
      for (int n = 0; n < 4; n++)
        acc[m][n] = __builtin_amdgcn_mfma_f32_16x16x32_bf16(af[m], bfr[n], acc[m][n], 0, 0, 0);
    if (more) {
      union { short8 s; unsigned u[4]; } w;
      w.u[0] = pk2(aR0.x, aR0.y); w.u[1] = pk2(aR0.z, aR0.w);
      w.u[2] = pk2(aR1.x, aR1.y); w.u[3] = pk2(aR1.z, aR1.w);
      *(short8*)(&As[cur ^ 1][ar * LDK + ak]) = w.s;
      *(short8*)(&Bs[cur ^ 1][bc * LDK + bk]) = bR0;
      *(short8*)(&Bs[cur ^ 1][bc * LDK + bk + 8]) = bR1;
    }
    __syncthreads();
  }

  // epilogue: tanh + v-dot; lane-reduce over cols, cross-wn reduce via LDS
  float vv[4], wsb[4];
  #pragma unroll
  for (int n = 0; n < 4; n++) {
    const int gc = col0 + wn*64 + n*16 + fr;
    vv[n]  = vw[gc];
    wsb[n] = Wsb[(size_t)bidx * ATT + gc];
  }
  const int rg = lane >> 4;
  #pragma unroll
  for (int m = 0; m < 4; m++) {
    float part[4] = {0.f, 0.f, 0.f, 0.f};
    #pragma unroll
    for (int n = 0; n < 4; n++) {
      #pragma unroll
      for (int r = 0; r < 4; r++)
        part[r] += vv[n] * fast_tanh(acc[m][n][r] + wsb[n]);
    }
    #pragma unroll
    for (int r = 0; r < 4; r++) {
      float p = part[r];
      p += __shfl_xor(p, 1);
      p += __shfl_xor(p, 2);
      p += __shfl_xor(p, 4);
      p += __shfl_xor(p, 8);
      if (fr == 0) eps[wn][wm*64 + m*16 + rg*4 + r] = p;
    }
  }
  __syncthreads();
  if (tid < BM) {
    float s = eps[0][tid] + eps[1][tid] + eps[2][tid] + eps[3][tid];
    epart[(size_t)nt * MTOT + row0 + tid] = s;
  }
}

// ---- softmax over S=2048 per batch row (sums the 2 partials), 512 thr ----
__global__ __launch_bounds__(512) void softmax_kernel(const float* __restrict__ epart,
                                                      float* __restrict__ out) {
  __shared__ float redmax[8];
  __shared__ float redsum[8];
  const int b = blockIdx.x, t = threadIdx.x;
  const float* e0 = epart + (size_t)b * SEQ;
  const float* e1 = epart + (size_t)MTOT + (size_t)b * SEQ;
  float vals[4];
  float mx = -1e30f;
  #pragma unroll
  for (int i = 0; i < 4; i++) {
    vals[i] = e0[t + i*512] + e1[t + i*512];
    mx = fmaxf(mx, vals[i]);
  }
  #pragma unroll
  for (int off = 1; off < 64; off <<= 1) mx = fmaxf(mx, __shfl_xor(mx, off));
  if ((t & 63) == 0) redmax[t >> 6] = mx;
  __syncthreads();
  mx = redmax[0];
  #pragma unroll
  for (int i = 1; i < 8; i++) mx = fmaxf(mx, redmax[i]);
  float sum = 0.f;
  #pragma unroll
  for (int i = 0; i < 4; i++) { vals[i] = expf(vals[i] - mx); sum += vals[i]; }
  #pragma unroll
  for (int off = 1; off < 64; off <<= 1) sum += __shfl_xor(sum, off);
  if ((t & 63) == 0) redsum[t >> 6] = sum;
  __syncthreads();
  float tot = 0.f;
  #pragma unroll
  for (int i = 0; i < 8; i++) tot += redsum[i];
  const float inv = 1.f / tot;
  #pragma unroll
  for (int i = 0; i < 4; i++) out[(size_t)b * SEQ + t + i*512] = vals[i] * inv;
}

extern "C" void kernel_launch(void* const* d_in, const int* in_sizes, int n_in,
                              void* d_out, int out_size, void* d_ws, size_t ws_size,
                              hipStream_t stream) {
  const float* dh  = (const float*)d_in[0];
  const float* enc = (const float*)d_in[1];
  const float* W_w = (const float*)d_in[2];
  const float* W_b = (const float*)d_in[3];
  const float* U_w = (const float*)d_in[4];
  const float* U_b = (const float*)d_in[5];
  const float* v_w = (const float*)d_in[6];
  float* out = (float*)d_out;

  char* ws = (char*)d_ws;
  float* epart = (float*)ws;                      // 512 KB (2 x MTOT f32)
  float* Wsb   = (float*)(ws + 512 * 1024);       // 64 KB
  short* U_wT  = (short*)(ws + 576 * 1024);       // 1 MB

  prep_kernel<<<256, 512, 0, stream>>>(U_w, U_wT, dh, W_w, W_b, U_b, Wsb);
  energy_kernel<<<1024, 512, 0, stream>>>(enc, U_wT, Wsb, v_w, epart);
  softmax_kernel<<<NBATCH, 512, 0, stream>>>(epart, out);
}